// Round 3
// baseline (1445.011 us; speedup 1.0000x reference)
//
#include <hip/hip_runtime.h>

// VecInt scaling-and-squaring, row-interleaved layout [z][y][c][x].
// disp = vel / 2^7; repeat 7x: disp = disp + trilinear_sample(disp, grid + disp).
//
// Round-2 flat SoA regressed (190us/step, 1.34 TB/s): channel stride 37.5 MiB
// is an exact multiple of the L1 (8 KiB) and L2 (256 KiB) set spans, so the
// 3 channel streams alias the same cache sets -> L1/L2 thrash -> L3 latency.
// Row-interleaved layout keeps 4B/voxel gather coalescing but puts channels
// 640 B apart (coprime with set spans) -> different sets, no aliasing.
// Size is exactly NTOT*3 floats, so d_out doubles as ping-pong buffer.

namespace {

constexpr int Dd = 160, Hh = 192, Ww = 160, Bb = 2;
constexpr int HW   = Hh * Ww;                // 30720
constexpr int VOX  = Dd * Hh * Ww;           // 4,915,200 per batch
constexpr int NTOT = Bb * VOX;               // 9,830,400 voxels
constexpr int ROWF = 3 * Ww;                 // 480 floats per (z,y) row triple

// ---- scale + AoS->row-interleave: out[row*480 + c*160 + x] = in[v*3+c]/128 ----
__global__ __launch_bounds__(256) void scale_t_k(const float* __restrict__ in,
                                                 float* __restrict__ out) {
    __shared__ float tile[768];
    int t = threadIdx.x;
    int v0 = blockIdx.x * 256;
    const float* src = in + (long long)v0 * 3;
    tile[t]       = src[t];
    tile[t + 256] = src[t + 256];
    tile[t + 512] = src[t + 512];
    __syncthreads();
    int v = v0 + t;
    int b = (v >= VOX) ? 1 : 0;
    int u = v - b * VOX;
    int z = u / HW;
    int rem = u - z * HW;
    int y = rem / Ww;
    int x = rem - y * Ww;
    int base = b * VOX * 3 + (z * Hh + y) * ROWF + x;
    constexpr float s = 1.0f / 128.0f;
    out[base]            = tile[3 * t + 0] * s;  // z-disp
    out[base + Ww]       = tile[3 * t + 1] * s;  // y-disp
    out[base + 2 * Ww]   = tile[3 * t + 2] * s;  // x-disp
}

// ---- one squaring step on row-interleaved layout ----
__device__ __forceinline__ void step_core(const float* __restrict__ A, int idx,
                                          float& r0, float& r1, float& r2,
                                          int& own) {
    int b = (idx >= VOX) ? 1 : 0;
    int v = idx - b * VOX;
    int z = v / HW;
    int rem = v - z * HW;
    int y = rem / Ww;
    int x = rem - y * Ww;

    int base3 = b * VOX * 3;
    own = base3 + (z * Hh + y) * ROWF + x;
    float d0 = A[own];            // z-displacement (ij: channel 0 = D axis)
    float d1 = A[own + Ww];       // y
    float d2 = A[own + 2 * Ww];   // x

    float lz = fminf(fmaxf((float)z + d0, 0.0f), (float)(Dd - 1));
    float ly = fminf(fmaxf((float)y + d1, 0.0f), (float)(Hh - 1));
    float lx = fminf(fmaxf((float)x + d2, 0.0f), (float)(Ww - 1));

    float fz = floorf(lz), fy = floorf(ly), fx = floorf(lx);
    int z0 = (int)fz, y0 = (int)fy, x0 = (int)fx;
    int z1 = min(z0 + 1, Dd - 1);
    int y1 = min(y0 + 1, Hh - 1);
    int x1 = min(x0 + 1, Ww - 1);
    float tz = lz - fz, ty = ly - fy, tx = lx - fx;
    float sz = 1.0f - tz, sy = 1.0f - ty, sx = 1.0f - tx;

    float w000 = sz * sy * sx, w001 = sz * sy * tx;
    float w010 = sz * ty * sx, w011 = sz * ty * tx;
    float w100 = tz * sy * sx, w101 = tz * sy * tx;
    float w110 = tz * ty * sx, w111 = tz * ty * tx;

    int r00 = base3 + (z0 * Hh + y0) * ROWF;
    int r01 = base3 + (z0 * Hh + y1) * ROWF;
    int r10 = base3 + (z1 * Hh + y0) * ROWF;
    int r11 = base3 + (z1 * Hh + y1) * ROWF;

    int p0 = r00 + x0, p1 = r00 + x1;
    int p2 = r01 + x0, p3 = r01 + x1;
    int p4 = r10 + x0, p5 = r10 + x1;
    int p6 = r11 + x0, p7 = r11 + x1;

    float a0 = w000 * A[p0] + w001 * A[p1] + w010 * A[p2] + w011 * A[p3]
             + w100 * A[p4] + w101 * A[p5] + w110 * A[p6] + w111 * A[p7];
    float a1 = w000 * A[p0 + Ww] + w001 * A[p1 + Ww]
             + w010 * A[p2 + Ww] + w011 * A[p3 + Ww]
             + w100 * A[p4 + Ww] + w101 * A[p5 + Ww]
             + w110 * A[p6 + Ww] + w111 * A[p7 + Ww];
    float a2 = w000 * A[p0 + 2 * Ww] + w001 * A[p1 + 2 * Ww]
             + w010 * A[p2 + 2 * Ww] + w011 * A[p3 + 2 * Ww]
             + w100 * A[p4 + 2 * Ww] + w101 * A[p5 + 2 * Ww]
             + w110 * A[p6 + 2 * Ww] + w111 * A[p7 + 2 * Ww];

    r0 = d0 + a0;
    r1 = d1 + a1;
    r2 = d2 + a2;
}

__global__ __launch_bounds__(256) void step_row_k(const float* __restrict__ A,
                                                  float* __restrict__ B) {
    int idx = blockIdx.x * blockDim.x + threadIdx.x;
    float r0, r1, r2;
    int own;
    step_core(A, idx, r0, r1, r2, own);
    B[own]          = r0;
    B[own + Ww]     = r1;
    B[own + 2 * Ww] = r2;
}

// ---- final step: row-interleaved in, AoS out (LDS repack) ----
__global__ __launch_bounds__(256) void step_final_k(const float* __restrict__ A,
                                                    float* __restrict__ out) {
    int t = threadIdx.x;
    int idx = blockIdx.x * 256 + t;
    float r0, r1, r2;
    int own;
    step_core(A, idx, r0, r1, r2, own);
    __shared__ float tile[768];
    tile[3 * t + 0] = r0;
    tile[3 * t + 1] = r1;
    tile[3 * t + 2] = r2;
    __syncthreads();
    float* dst = out + (long long)blockIdx.x * 768;
    dst[t]       = tile[t];
    dst[t + 256] = tile[t + 256];
    dst[t + 512] = tile[t + 512];
}

}  // namespace

extern "C" void kernel_launch(void* const* d_in, const int* in_sizes, int n_in,
                              void* d_out, int out_size, void* d_ws, size_t ws_size,
                              hipStream_t stream) {
    const float* vel = (const float*)d_in[0];
    float* out = (float*)d_out;
    float* W   = (float*)d_ws;   // row-interleaved buffer A (118 MB)
    float* O   = (float*)d_out;  // row-interleaved buffer B = d_out as scratch

    constexpr int blk = 256;
    constexpr int grd = NTOT / blk;  // 38400, exact

    scale_t_k<<<grd, blk, 0, stream>>>(vel, W);

    // steps 1..6 ping-pong W <-> O (ends in W)
    float* a = W;
    float* b = O;
    for (int it = 0; it < 6; ++it) {
        step_row_k<<<grd, blk, 0, stream>>>(a, b);
        float* tmp = a; a = b; b = tmp;
    }
    // step 7: row-interleaved -> AoS into d_out
    step_final_k<<<grd, blk, 0, stream>>>(a, out);
}

// Round 4
// 750.050 us; speedup vs baseline: 1.9266x; 1.9266x over previous
//
#include <hip/hip_runtime.h>

// VecInt scaling-and-squaring. AoS fp32 layout [z][y][x][c] (c = z,y,x disp).
//
// R1-R3 evidence: per-VMEM-instruction cost ~16cyc + ~1.7cyc/line (divergent
// address coalescing) -> global-gather AoS kernel is at its floor (344cyc/wave,
// 86us/step). Fix: move gathers to the LDS pipe. Steps 1-5 have |d| <
// 2^(k-1)*max|vel|/128 < 0.75 voxels -> +-1 halo suffices; blocks march z with
// a 4-slot rolling plane window (46KB LDS), coalesced float4 staging, 8 LDS
// gathers/voxel, masked global fallback for out-of-window lanes (correctness
// never depends on the displacement bound). Steps 6-7 (|d| up to ~3) use the
// proven global-gather kernel.

namespace {

constexpr int Dd = 160, Hh = 192, Ww = 160, Bb = 2;
constexpr int HW   = Hh * Ww;                 // 30720
constexpr int VOX  = Dd * HW;                 // 4,915,200 per batch
constexpr int NTOT = Bb * VOX;                // 9,830,400 voxels
constexpr long long NFLT = (long long)NTOT * 3;
constexpr int ROWF = Ww * 3;                  // 480 floats per (z,y) row

// ---- disp0 = vel / 128 (straight AoS copy) ----
__global__ __launch_bounds__(256) void scale_k(const float* __restrict__ in,
                                               float* __restrict__ out) {
    long long i = (long long)blockIdx.x * blockDim.x + threadIdx.x;
    const long long n4 = NFLT / 4;
    if (i < n4) {
        float4 v = reinterpret_cast<const float4*>(in)[i];
        constexpr float s = 1.0f / 128.0f;
        v.x *= s; v.y *= s; v.z *= s; v.w *= s;
        reinterpret_cast<float4*>(out)[i] = v;
    }
}

// ---- global-gather step (R1 kernel, used for steps 6,7) ----
__global__ __launch_bounds__(256) void step_k(const float* __restrict__ disp,
                                              float* __restrict__ out) {
    int idx = blockIdx.x * blockDim.x + threadIdx.x;
    if (idx >= NTOT) return;

    int b = (idx >= VOX) ? 1 : 0;
    int v = idx - b * VOX;
    int z = v / HW;
    int rem = v - z * HW;
    int y = rem / Ww;
    int x = rem - y * Ww;

    const float* __restrict__ vol = disp + (long long)b * VOX * 3;
    int base3 = idx * 3;
    float d0 = disp[base3 + 0];
    float d1 = disp[base3 + 1];
    float d2 = disp[base3 + 2];

    float lz = fminf(fmaxf((float)z + d0, 0.0f), (float)(Dd - 1));
    float ly = fminf(fmaxf((float)y + d1, 0.0f), (float)(Hh - 1));
    float lx = fminf(fmaxf((float)x + d2, 0.0f), (float)(Ww - 1));

    float fz = floorf(lz), fy = floorf(ly), fx = floorf(lx);
    int z0 = (int)fz, y0 = (int)fy, x0 = (int)fx;
    int z1 = min(z0 + 1, Dd - 1);
    int y1 = min(y0 + 1, Hh - 1);
    int x1 = min(x0 + 1, Ww - 1);
    float tz = lz - fz, ty = ly - fy, tx = lx - fx;
    float sz = 1.0f - tz, sy = 1.0f - ty, sx = 1.0f - tx;

    float w000 = sz * sy * sx, w001 = sz * sy * tx;
    float w010 = sz * ty * sx, w011 = sz * ty * tx;
    float w100 = tz * sy * sx, w101 = tz * sy * tx;
    float w110 = tz * ty * sx, w111 = tz * ty * tx;

    int r00 = (z0 * Hh + y0) * Ww;
    int r01 = (z0 * Hh + y1) * Ww;
    int r10 = (z1 * Hh + y0) * Ww;
    int r11 = (z1 * Hh + y1) * Ww;

    const float* p000 = vol + (r00 + x0) * 3;
    const float* p001 = vol + (r00 + x1) * 3;
    const float* p010 = vol + (r01 + x0) * 3;
    const float* p011 = vol + (r01 + x1) * 3;
    const float* p100 = vol + (r10 + x0) * 3;
    const float* p101 = vol + (r10 + x1) * 3;
    const float* p110 = vol + (r11 + x0) * 3;
    const float* p111 = vol + (r11 + x1) * 3;

    float a0 = w000 * p000[0] + w001 * p001[0] + w010 * p010[0] + w011 * p011[0]
             + w100 * p100[0] + w101 * p101[0] + w110 * p110[0] + w111 * p111[0];
    float a1 = w000 * p000[1] + w001 * p001[1] + w010 * p010[1] + w011 * p011[1]
             + w100 * p100[1] + w101 * p101[1] + w110 * p110[1] + w111 * p111[1];
    float a2 = w000 * p000[2] + w001 * p001[2] + w010 * p010[2] + w011 * p011[2]
             + w100 * p100[2] + w101 * p101[2] + w110 * p110[2] + w111 * p111[2];

    out[base3 + 0] = d0 + a0;
    out[base3 + 1] = d1 + a1;
    out[base3 + 2] = d2 + a2;
}

// ---- rolling z-march step with LDS plane window (steps 1..5, H=1) ----
template <int H, int TY>
__global__ __launch_bounds__(TY * Ww) void march_k(const float* __restrict__ A,
                                                   float* __restrict__ B) {
    constexpr int R = TY + 2 * H;        // staged rows per plane slot
    constexpr int W = 2 * H + 2;         // ring slots (one spare for prefetch)
    constexpr int SLOTF = R * ROWF;      // floats per slot
    constexpr int NTHR = TY * Ww;        // block threads
    constexpr int ZCHUNK = 20;           // planes per block (160/8 chunks)
    __shared__ float lds[W * SLOTF];     // H=1,TY=4: 46,080 B

    const int tid = threadIdx.x;
    const int ty0 = blockIdx.x * TY;     // 48 y-tiles
    const int c0  = blockIdx.y * ZCHUNK; // 8 z-chunks
    const int b   = blockIdx.z;          // batch
    const int base3 = b * VOX * 3;

    const int x  = tid % Ww;
    const int ry = tid / Ww;             // 0..TY-1
    const int gy = ty0 + ry;

    const int ylo = max(ty0 - H, 0);
    const int yhi = min(ty0 + TY - 1 + H, Hh - 1);
    const int cnt4 = (yhi - ylo + 1) * (ROWF / 4);          // float4s to stage
    const int ldsYoff4 = (ylo - (ty0 - H)) * (ROWF / 4);

    // stage plane p (rows [ylo,yhi]) into ring slot p%W; coalesced flat copy
    auto stage = [&](int p) {
        if (p < 0 || p >= Dd) return;
        const float4* src =
            reinterpret_cast<const float4*>(A + base3 + (p * Hh + ylo) * ROWF);
        float4* dst = reinterpret_cast<float4*>(lds) + (p % W) * (SLOTF / 4)
                    + ldsYoff4;
        for (int f = tid; f < cnt4; f += NTHR) dst[f] = src[f];
    };

    for (int p = c0 - H; p <= c0 + H; ++p) stage(p);
    __syncthreads();

    for (int z = c0; z < c0 + ZCHUNK; ++z) {
        // prefetch next plane into the spare slot (nobody reads it this iter)
        stage(z + H + 1);

        // own displacement from the LDS window (always in-window)
        const int rowOwn = gy - (ty0 - H);
        const float* own = lds + (z % W) * SLOTF + rowOwn * ROWF + x * 3;
        float d0 = own[0], d1 = own[1], d2 = own[2];

        float lz = fminf(fmaxf((float)z + d0, 0.0f), (float)(Dd - 1));
        float ly = fminf(fmaxf((float)gy + d1, 0.0f), (float)(Hh - 1));
        float lx = fminf(fmaxf((float)x + d2, 0.0f), (float)(Ww - 1));

        float fz = floorf(lz), fy = floorf(ly), fx = floorf(lx);
        int z0 = (int)fz, y0 = (int)fy, x0 = (int)fx;
        int z1 = min(z0 + 1, Dd - 1);
        int y1 = min(y0 + 1, Hh - 1);
        int x1 = min(x0 + 1, Ww - 1);
        float tz = lz - fz, ty = ly - fy, tx = lx - fx;
        float sz = 1.0f - tz, sy = 1.0f - ty, sx = 1.0f - tx;

        float g[8][3];
        bool inw = (z0 >= z - H) && (z1 <= z + H) &&
                   (y0 >= ty0 - H) && (y1 <= ty0 + TY - 1 + H);
        if (inw) {
            int s0 = z0 % W;           // z0 >= 0 (clipped)
            int s1 = z1 % W;
            const float* P00 = lds + s0 * SLOTF + (y0 - (ty0 - H)) * ROWF;
            const float* P01 = lds + s0 * SLOTF + (y1 - (ty0 - H)) * ROWF;
            const float* P10 = lds + s1 * SLOTF + (y0 - (ty0 - H)) * ROWF;
            const float* P11 = lds + s1 * SLOTF + (y1 - (ty0 - H)) * ROWF;
            int xa = x0 * 3, xb = x1 * 3;
            g[0][0] = P00[xa + 0]; g[0][1] = P00[xa + 1]; g[0][2] = P00[xa + 2];
            g[1][0] = P00[xb + 0]; g[1][1] = P00[xb + 1]; g[1][2] = P00[xb + 2];
            g[2][0] = P01[xa + 0]; g[2][1] = P01[xa + 1]; g[2][2] = P01[xa + 2];
            g[3][0] = P01[xb + 0]; g[3][1] = P01[xb + 1]; g[3][2] = P01[xb + 2];
            g[4][0] = P10[xa + 0]; g[4][1] = P10[xa + 1]; g[4][2] = P10[xa + 2];
            g[5][0] = P10[xb + 0]; g[5][1] = P10[xb + 1]; g[5][2] = P10[xb + 2];
            g[6][0] = P11[xa + 0]; g[6][1] = P11[xa + 1]; g[6][2] = P11[xa + 2];
            g[7][0] = P11[xb + 0]; g[7][1] = P11[xb + 1]; g[7][2] = P11[xb + 2];
        } else {
            // rare fallback: |d| exceeded H; gather from global (exact math)
            const float* G = A + base3;
            const float* Q00 = G + (z0 * Hh + y0) * ROWF;
            const float* Q01 = G + (z0 * Hh + y1) * ROWF;
            const float* Q10 = G + (z1 * Hh + y0) * ROWF;
            const float* Q11 = G + (z1 * Hh + y1) * ROWF;
            int xa = x0 * 3, xb = x1 * 3;
            g[0][0] = Q00[xa + 0]; g[0][1] = Q00[xa + 1]; g[0][2] = Q00[xa + 2];
            g[1][0] = Q00[xb + 0]; g[1][1] = Q00[xb + 1]; g[1][2] = Q00[xb + 2];
            g[2][0] = Q01[xa + 0]; g[2][1] = Q01[xa + 1]; g[2][2] = Q01[xa + 2];
            g[3][0] = Q01[xb + 0]; g[3][1] = Q01[xb + 1]; g[3][2] = Q01[xb + 2];
            g[4][0] = Q10[xa + 0]; g[4][1] = Q10[xa + 1]; g[4][2] = Q10[xa + 2];
            g[5][0] = Q10[xb + 0]; g[5][1] = Q10[xb + 1]; g[5][2] = Q10[xb + 2];
            g[6][0] = Q11[xa + 0]; g[6][1] = Q11[xa + 1]; g[6][2] = Q11[xa + 2];
            g[7][0] = Q11[xb + 0]; g[7][1] = Q11[xb + 1]; g[7][2] = Q11[xb + 2];
        }

        float w000 = sz * sy * sx, w001 = sz * sy * tx;
        float w010 = sz * ty * sx, w011 = sz * ty * tx;
        float w100 = tz * sy * sx, w101 = tz * sy * tx;
        float w110 = tz * ty * sx, w111 = tz * ty * tx;

        float a0 = w000 * g[0][0] + w001 * g[1][0] + w010 * g[2][0] + w011 * g[3][0]
                 + w100 * g[4][0] + w101 * g[5][0] + w110 * g[6][0] + w111 * g[7][0];
        float a1 = w000 * g[0][1] + w001 * g[1][1] + w010 * g[2][1] + w011 * g[3][1]
                 + w100 * g[4][1] + w101 * g[5][1] + w110 * g[6][1] + w111 * g[7][1];
        float a2 = w000 * g[0][2] + w001 * g[1][2] + w010 * g[2][2] + w011 * g[3][2]
                 + w100 * g[4][2] + w101 * g[5][2] + w110 * g[6][2] + w111 * g[7][2];

        float* o = B + base3 + (z * Hh + gy) * ROWF + x * 3;
        o[0] = d0 + a0;
        o[1] = d1 + a1;
        o[2] = d2 + a2;

        __syncthreads();
    }
}

}  // namespace

extern "C" void kernel_launch(void* const* d_in, const int* in_sizes, int n_in,
                              void* d_out, int out_size, void* d_ws, size_t ws_size,
                              hipStream_t stream) {
    const float* vel = (const float*)d_in[0];
    float* out = (float*)d_out;
    float* W   = (float*)d_ws;   // buffer A (118 MB)
    float* O   = (float*)d_out;  // buffer B = d_out doubles as scratch

    // disp0 = vel / 128 -> ws
    {
        long long n4 = NFLT / 4;
        int blk = 256;
        int grd = (int)((n4 + blk - 1) / blk);
        scale_k<<<grd, blk, 0, stream>>>(vel, W);
    }

    dim3 mgrid(Hh / 4, Dd / 20, Bb);   // 48 x 8 x 2 = 768 blocks
    int  mblk = 4 * Ww;                // 640 threads

    float* a = W;
    float* b = O;
    // steps 1..5: |d| < 0.75 -> H=1 march
    for (int it = 0; it < 5; ++it) {
        march_k<1, 4><<<mgrid, mblk, 0, stream>>>(a, b);
        float* t = a; a = b; b = t;
    }
    // steps 6,7: |d| up to ~3 -> global-gather kernel
    int blk = 256;
    int grd = (NTOT + blk - 1) / blk;
    for (int it = 0; it < 2; ++it) {
        step_k<<<grd, blk, 0, stream>>>(a, b);
        float* t = a; a = b; b = t;
    }
    // 7 steps total (odd) starting from ws -> final result lands in d_out.
}